// Round 4
// baseline (2611.123 us; speedup 1.0000x reference)
//
#include <hip/hip_runtime.h>

typedef __attribute__((ext_vector_type(8))) short short8;
typedef __attribute__((ext_vector_type(4))) float floatx4;
typedef __attribute__((ext_vector_type(8))) unsigned short ushort8;

constexpr int Mdim = 8192;    // B*S
constexpr int Kdim = 4096;    // IN
constexpr int Ndim = 11008;   // OUT
constexpr int BM = 128, BN = 128, BK = 64;
constexpr int NGRP = 32;      // IN/GROUP = 4096/128

__device__ __forceinline__ unsigned short f32_to_bf16(float f) {
    unsigned u = __builtin_bit_cast(unsigned, f);
    u += 0x7fffu + ((u >> 16) & 1u);     // round-to-nearest-even
    return (unsigned short)(u >> 16);
}

// Fused dequant + bf16 MFMA GEMM. Zero workspace.
// All float tensors are fp32 in device memory (harness converts the reference's
// fp16 to fp32); weight is int32 (harness widens int8).
// C[M][N] = A[M][K] * (W[N][K] * scale[N][K/128])^T + bias
__global__ __launch_bounds__(256) void wq8_gemm_kernel(
        const float* __restrict__ A,      // [M][K] fp32
        const int* __restrict__ W,        // [N][K] int32
        const float* __restrict__ scale,  // [N][NGRP] fp32
        const float* __restrict__ bias,   // [N] fp32
        float* __restrict__ C) {          // [M][N] fp32
    __shared__ unsigned short sA[BM * BK];
    __shared__ unsigned short sB[BN * BK];

    const int tid  = threadIdx.x;
    const int lane = tid & 63;
    const int wave = tid >> 6;
    const int m0 = blockIdx.y * BM;
    const int n0 = blockIdx.x * BN;

    // staging map: thread tid covers row = (tid>>3) + 32*it, cols (tid&7)*8 .. +7
    const int srow = tid >> 3;          // 0..31
    const int scol = (tid & 7) * 8;     // element offset in K

    const int wm = (wave >> 1) * 64;    // 2x2 waves over 128x128
    const int wn = (wave & 1) * 64;
    const int fr = lane & 15;           // frag row (m for A, n for B), and C col
    const int fk = (lane >> 4) * 8;     // frag k offset

    floatx4 acc[4][4] = {};

    const float* ga0 = A + (long)(m0 + srow) * Kdim + scol;
    const int*   gw0 = W + (long)(n0 + srow) * Kdim + scol;

    for (int k0 = 0; k0 < Kdim; k0 += BK) {
        const int grp = k0 >> 7;        // one scale group per K-tile (BK=64 <= GROUP=128)

        // ---- load A tile (fp32) and W tile (int32) ----
        float4 rax[4][2];
        int4   rw[4][2];
        float  sc[4];
        #pragma unroll
        for (int it = 0; it < 4; ++it) {
            const float* ap = ga0 + (long)it * 32 * Kdim + k0;
            rax[it][0] = *(const float4*)(ap);
            rax[it][1] = *(const float4*)(ap + 4);
            const int* wp = gw0 + (long)it * 32 * Kdim + k0;
            rw[it][0] = *(const int4*)(wp);
            rw[it][1] = *(const int4*)(wp + 4);
            sc[it] = scale[(long)(n0 + srow + it * 32) * NGRP + grp];
        }

        // ---- stage: A fp32->bf16, W dequantized to bf16 ----
        #pragma unroll
        for (int it = 0; it < 4; ++it) {
            ushort8 av;
            av[0] = f32_to_bf16(rax[it][0].x);
            av[1] = f32_to_bf16(rax[it][0].y);
            av[2] = f32_to_bf16(rax[it][0].z);
            av[3] = f32_to_bf16(rax[it][0].w);
            av[4] = f32_to_bf16(rax[it][1].x);
            av[5] = f32_to_bf16(rax[it][1].y);
            av[6] = f32_to_bf16(rax[it][1].z);
            av[7] = f32_to_bf16(rax[it][1].w);
            *(ushort8*)(sA + it * 2048 + tid * 8) = av;

            ushort8 o;
            const float s = sc[it];
            o[0] = f32_to_bf16((float)rw[it][0].x * s);
            o[1] = f32_to_bf16((float)rw[it][0].y * s);
            o[2] = f32_to_bf16((float)rw[it][0].z * s);
            o[3] = f32_to_bf16((float)rw[it][0].w * s);
            o[4] = f32_to_bf16((float)rw[it][1].x * s);
            o[5] = f32_to_bf16((float)rw[it][1].y * s);
            o[6] = f32_to_bf16((float)rw[it][1].z * s);
            o[7] = f32_to_bf16((float)rw[it][1].w * s);
            *(ushort8*)(sB + it * 2048 + tid * 8) = o;
        }
        __syncthreads();

        #pragma unroll
        for (int kk = 0; kk < BK; kk += 32) {
            short8 af[4], bfr[4];
            #pragma unroll
            for (int i = 0; i < 4; ++i)
                af[i] = *(const short8*)(sA + (wm + i * 16 + fr) * BK + kk + fk);
            #pragma unroll
            for (int j = 0; j < 4; ++j)
                bfr[j] = *(const short8*)(sB + (wn + j * 16 + fr) * BK + kk + fk);
            #pragma unroll
            for (int i = 0; i < 4; ++i)
                #pragma unroll
                for (int j = 0; j < 4; ++j)
                    acc[i][j] = __builtin_amdgcn_mfma_f32_16x16x32_bf16(
                        af[i], bfr[j], acc[i][j], 0, 0, 0);
        }
        __syncthreads();
    }

    // epilogue: C/D layout col=lane&15, row=(lane>>4)*4+reg  [m89/m91]
    float bv[4];
    #pragma unroll
    for (int j = 0; j < 4; ++j)
        bv[j] = bias[n0 + wn + j * 16 + fr];

    const int r0 = (lane >> 4) * 4;
    #pragma unroll
    for (int i = 0; i < 4; ++i) {
        #pragma unroll
        for (int r = 0; r < 4; ++r) {
            long row = m0 + wm + i * 16 + r0 + r;
            float* cp = C + row * Ndim + n0 + wn + fr;
            #pragma unroll
            for (int j = 0; j < 4; ++j)
                cp[j * 16] = acc[i][j][r] + bv[j];
        }
    }
}

extern "C" void kernel_launch(void* const* d_in, const int* in_sizes, int n_in,
                              void* d_out, int out_size, void* d_ws, size_t ws_size,
                              hipStream_t stream) {
    const float* x     = (const float*)d_in[0];  // fp32 [B,S,IN] (fp16 widened by harness)
    const int*   w     = (const int*)d_in[1];    // int32 [OUT,IN] (int8 widened)
    const float* scale = (const float*)d_in[2];  // fp32 [OUT,IN/128]
    const float* bias  = (const float*)d_in[3];  // fp32 [OUT]
    float* out = (float*)d_out;                  // fp32 [B,S,OUT]

    wq8_gemm_kernel<<<dim3(Ndim / BN, Mdim / BM), 256, 0, stream>>>(x, w, scale, bias, out);
}